// Round 4
// baseline (1633.055 us; speedup 1.0000x reference)
//
#include <hip/hip_runtime.h>
#include <math.h>

// SLSTM block step. B=2048 H=4096 NH=4 HS=1024 convK=4
// GEMMs on matrix cores via bf16x2 split (3 MFMA products, fp32 accum).
// All A operands pre-split to bf16 hi/lo fragment-order chunks; gemm stages A
// with global_load_lds (no VALU, conflict-free LDS). W split in-kernel
// (7-op RNE), reg-staged, conflict-free ds_writes. Single-buffer 48KB LDS.
//
// d_out slots (floats, each B*H=8M):
//   [0) out | [1,4) new_conv_state (B,3,H) | [4) y | [5) cell | [6) norm | [7) max
// Slot timeline (each split plane-pair is exactly 32MB = one slot):
//   prep:    writes xact_fp32 -> slot7, ncs -> slots1-3 (xn = plane 2)
//   tile:    slot7->xact_split(slot0), ncs.xn->xn_split(slot4), rst->ws(32MB)
//   gemm_zo: reads slot4+ws, writes z->slot6, o->slot7
//   gemm_if: reads slot0+ws, writes i->slot4, f->slot5
//   post:    reads slots4-7, writes y,cell,norm,max in place + out->slot0
// Split chunk layout per matrix: ((rf*128 + ksg)*2 + pl)*1024 + l*16,
//   rf=row/16, ksg=col/32 (gemm uses ksg = head*32 + ks), pl=hi/lo,
//   lane l = (row rf*16+(l&15), k ksg*32+(l>>4)*8) -- MFMA fragment order.
// Requires ws_size >= 33554432 (32MB).

#define Bn 2048
#define Hn 4096
#define NHn 4
#define HSn 1024

typedef __attribute__((ext_vector_type(8))) short short8;
typedef __attribute__((ext_vector_type(4))) float f32x4;
typedef unsigned int uint;

// ---------------------------------------------------------------- prep ------
__global__ __launch_bounds__(256) void prep_kernel(
    const float* __restrict__ x, const float* __restrict__ cs,
    const float* __restrict__ ln_w, const float* __restrict__ conv_w,
    const float* __restrict__ conv_b, float* __restrict__ xact_out,
    float* __restrict__ ncs) {
  const int b = blockIdx.x;
  const int t = threadIdx.x;
  const float* xr = x + (size_t)b * Hn;

  float4 xv[4];
  float s = 0.f, s2 = 0.f;
#pragma unroll
  for (int i = 0; i < 4; ++i) {
    xv[i] = *reinterpret_cast<const float4*>(xr + i * 1024 + t * 4);
    s += xv[i].x + xv[i].y + xv[i].z + xv[i].w;
    s2 += xv[i].x * xv[i].x + xv[i].y * xv[i].y + xv[i].z * xv[i].z +
          xv[i].w * xv[i].w;
  }
#pragma unroll
  for (int off = 32; off >= 1; off >>= 1) {
    s += __shfl_down(s, off);
    s2 += __shfl_down(s2, off);
  }
  __shared__ float red[10];
  const int lane = t & 63, wv = t >> 6;
  if (lane == 0) { red[wv] = s; red[4 + wv] = s2; }
  __syncthreads();
  if (t == 0) {
    float ts = red[0] + red[1] + red[2] + red[3];
    float ts2 = red[4] + red[5] + red[6] + red[7];
    float mean = ts * (1.f / Hn);
    float var = ts2 * (1.f / Hn) - mean * mean;
    red[8] = mean;
    red[9] = rsqrtf(var + 1e-5f);
  }
  __syncthreads();
  const float mean = red[8], rstd = red[9];

#pragma unroll
  for (int i = 0; i < 4; ++i) {
    const int h = i * 1024 + t * 4;
    float lw[4], cs0[4], cs1[4], cs2[4], cb[4];
    *(float4*)lw = *(const float4*)(ln_w + h);
    *(float4*)cs0 = *(const float4*)(cs + ((size_t)b * 3 + 0) * Hn + h);
    *(float4*)cs1 = *(const float4*)(cs + ((size_t)b * 3 + 1) * Hn + h);
    *(float4*)cs2 = *(const float4*)(cs + ((size_t)b * 3 + 2) * Hn + h);
    *(float4*)cb = *(const float4*)(conv_b + h);
    const float xvi[4] = {xv[i].x, xv[i].y, xv[i].z, xv[i].w};
    float xnv[4], xav[4];
#pragma unroll
    for (int j = 0; j < 4; ++j) {
      const float xnj = (xvi[j] - mean) * rstd * lw[j];
      float cw[4];
      *(float4*)cw = *(const float4*)(conv_w + (size_t)(h + j) * 4);
      const float xc =
          cs0[j] * cw[0] + cs1[j] * cw[1] + cs2[j] * cw[2] + xnj * cw[3] + cb[j];
      xav[j] = xc / (1.f + expf(-xc));  // silu
      xnv[j] = xnj;
    }
    *(float4*)(xact_out + (size_t)b * Hn + h) = *(float4*)xav;
    *(float4*)(ncs + ((size_t)b * 3 + 0) * Hn + h) = *(float4*)cs1;
    *(float4*)(ncs + ((size_t)b * 3 + 1) * Hn + h) = *(float4*)cs2;
    *(float4*)(ncs + ((size_t)b * 3 + 2) * Hn + h) = *(float4*)xnv;
  }
}

// ------------------------------------------------------- bf16x2 helpers -----
__device__ __forceinline__ void split8(const float4 a, const float4 b,
                                       uint4& hi, uint4& lo) {
  float f[8] = {a.x, a.y, a.z, a.w, b.x, b.y, b.z, b.w};
  uint hw[8], lw[8];
#pragma unroll
  for (int j = 0; j < 8; ++j) {
    uint u = __float_as_uint(f[j]);
    uint r = (u + 0x7FFFu + ((u >> 16) & 1u)) & 0xFFFF0000u;  // RNE hi bits
    float res = f[j] - __uint_as_float(r);                    // exact residual
    uint u2 = __float_as_uint(res);
    uint r2 = u2 + 0x7FFFu + ((u2 >> 16) & 1u);               // RNE lo
    hw[j] = r >> 16;
    lw[j] = r2 >> 16;
  }
  hi = make_uint4(hw[0] | (hw[1] << 16), hw[2] | (hw[3] << 16),
                  hw[4] | (hw[5] << 16), hw[6] | (hw[7] << 16));
  lo = make_uint4(lw[0] | (lw[1] << 16), lw[2] | (lw[3] << 16),
                  lw[4] | (lw[5] << 16), lw[6] | (lw[7] << 16));
}

__device__ __forceinline__ void glds16(const void* g, void* l) {
  __builtin_amdgcn_global_load_lds(
      (const __attribute__((address_space(1))) uint*)g,
      (__attribute__((address_space(3))) uint*)l, 16, 0, 0);
}

// ---------------------------------------------------------------- tile ------
// Split the three A matrices into bf16 hi/lo fragment-order chunk planes.
// grid (128 rf, 3 mat) x 256 thr. Reads: per (rf,ks) a 16x32 fp32 subtile
// (one 128B line per row). Writes: wave -> contiguous 1KB (perfect).
__global__ __launch_bounds__(256) void tile_kernel(
    const float* __restrict__ src0, const float* __restrict__ src1,
    const float* __restrict__ src2, char* __restrict__ dst0,
    char* __restrict__ dst1, char* __restrict__ dst2) {
  const int rf = blockIdx.x;
  const int mat = blockIdx.y;
  const float* src = mat == 0 ? src0 : (mat == 1 ? src1 : src2);
  char* dst = mat == 0 ? dst0 : (mat == 1 ? dst1 : dst2);
  const size_t lda = (mat == 1) ? (size_t)(3 * Hn) : (size_t)Hn;

#pragma unroll 4
  for (int j = 0; j < 32; ++j) {
    const int sid = threadIdx.x + j * 256;
    const int ks = sid >> 6, l = sid & 63;
    const int row = rf * 16 + (l & 15);
    const int k = ks * 32 + (l >> 4) * 8;
    const float* p = src + (size_t)row * lda + k;
    float4 a = *(const float4*)p;
    float4 b = *(const float4*)(p + 4);
    uint4 hi, lo;
    split8(a, b, hi, lo);
    char* cb = dst + ((size_t)rf * 128 + ks) * 2048;
    *(uint4*)(cb + l * 16) = hi;
    *(uint4*)(cb + 1024 + l * 16) = lo;
  }
}

// ---------------------------------------------------------------- gemm ------
// Block: 256 rows x (64 cols gate0 + 64 cols gate1), K=2048 (in:1024, st:1024).
// 512 thr = 8 waves (wm 0..3 rows x wn 0..1 gate), per-wave 64x64 output =
// 4x4 fragments 16x16, 3 MFMA per fragment per K-step (BK=32).
// LDS 48KB single buffer: A chunks [rf16][pl] 32KB | W chunks [g][nf][pl] 16KB.
// Per iter: {glds A + ds_write W-split -> barrier -> frag reads + 48 MFMA
//            (+ next-W reg load & split overlapped) -> barrier}.
__global__ __launch_bounds__(512, 4) void gemm_pair_mfma(
    const char* __restrict__ Asp_in, const char* __restrict__ Asp_st,
    const float* __restrict__ W0in, const float* __restrict__ W0st,
    const float* __restrict__ W1in, const float* __restrict__ W1st,
    const float* __restrict__ bias0, const float* __restrict__ bias1,
    float* __restrict__ O0, float* __restrict__ O1) {
  __shared__ char lds[49152];

  // 2D XCD clustering: XCD xc covers head=xc>>1, mt-half=xc&1 (A+W L2 reuse)
  const int bid = blockIdx.x;  // 512
  const int xc = bid & 7, jj = bid >> 3;
  const int panel = (xc >> 1) * 16 + (jj >> 2);   // head*16+nt
  const int mt = (xc & 1) * 4 + (jj & 3);
  const int head = panel >> 4, nt = panel & 15;

  const int t = threadIdx.x;
  const int w = t >> 6, l = t & 63;
  const int wm = w >> 1, wn = w & 1;
  const int l15 = l & 15, l4 = l >> 4;
  const int w4 = w * 4;

  // A glds sources: wave w stages chunks c=w*4+i (rfl=c>>1, pl=c&1)
  const char* abase_in[4];
  const char* abase_st[4];
#pragma unroll
  for (int i = 0; i < 4; ++i) {
    const int c = w4 + i, rfl = c >> 1, pl = c & 1;
    const size_t off =
        (((size_t)(mt * 16 + rfl) * 128 + head * 32) * 2 + pl) * 1024 + l * 16;
    abase_in[i] = Asp_in + off;
    abase_st[i] = Asp_st + off;
  }

  // W staging: g = t>>7 (k-octet, wave-uniform), cc = t&127 (gate<<6|col)
  const int g = t >> 7, cc = t & 127;
  const int gate = cc >> 6, c64 = cc & 63, nfw = c64 >> 4;
  const float* wsrc_in = (gate ? W1in : W0in) + (size_t)head * (HSn * HSn) +
                         (size_t)(nt * 64 + c64) * HSn + g * 8;
  const float* wsrc_st = (gate ? W1st : W0st) + (size_t)head * (HSn * HSn) +
                         (size_t)(nt * 64 + c64) * HSn + g * 8;
  const int wdoff =
      32768 + ((gate * 4 + nfw) * 2) * 1024 + ((c64 & 15) + 16 * g) * 16;

  float4 wra, wrb;
  uint4 whi, wlo;
  wra = *(const float4*)wsrc_in;
  wrb = *(const float4*)(wsrc_in + 4);
  split8(wra, wrb, whi, wlo);

  f32x4 acc[4][4] = {};

#pragma unroll 1
  for (int tt = 0; tt < 64; ++tt) {
    // ---- staging phase (buffer free after trailing barrier)
    if (tt < 32) {
#pragma unroll
      for (int i = 0; i < 4; ++i)
        glds16(abase_in[i] + (size_t)tt * 2048, lds + (w4 + i) * 1024);
    } else {
#pragma unroll
      for (int i = 0; i < 4; ++i)
        glds16(abase_st[i] + (size_t)(tt - 32) * 2048, lds + (w4 + i) * 1024);
    }
    *(uint4*)(lds + wdoff) = whi;
    *(uint4*)(lds + wdoff + 1024) = wlo;
    __syncthreads();  // drain glds + ds_writes

    // ---- compute phase; next-tile W load issued here (drains at barrier 2)
    if (tt < 63) {
      const int nx = tt + 1;
      const float* wp =
          (nx < 32) ? wsrc_in + nx * 32 : wsrc_st + (nx - 32) * 32;
      wra = *(const float4*)wp;
      wrb = *(const float4*)(wp + 4);
    }
    short8 wh[4], wl[4];
#pragma unroll
    for (int nf = 0; nf < 4; ++nf) {
      const char* wb = lds + 32768 + ((wn * 4 + nf) * 2) * 1024 + l * 16;
      wh[nf] = *(const short8*)wb;
      wl[nf] = *(const short8*)(wb + 1024);
    }
    __builtin_amdgcn_s_setprio(1);
#pragma unroll
    for (int mf = 0; mf < 4; ++mf) {
      const char* ab = lds + ((wm * 4 + mf) * 2) * 1024 + l * 16;
      short8 ah = *(const short8*)ab;
      short8 al = *(const short8*)(ab + 1024);
#pragma unroll
      for (int nf = 0; nf < 4; ++nf) {
        acc[mf][nf] = __builtin_amdgcn_mfma_f32_16x16x32_bf16(ah, wh[nf],
                                                              acc[mf][nf], 0, 0, 0);
        acc[mf][nf] = __builtin_amdgcn_mfma_f32_16x16x32_bf16(al, wh[nf],
                                                              acc[mf][nf], 0, 0, 0);
        acc[mf][nf] = __builtin_amdgcn_mfma_f32_16x16x32_bf16(ah, wl[nf],
                                                              acc[mf][nf], 0, 0, 0);
      }
    }
    __builtin_amdgcn_s_setprio(0);
    if (tt < 63) split8(wra, wrb, whi, wlo);  // VALU, under MFMA shadow
    __syncthreads();  // readers done before next staging overwrites
  }

  // ---- epilogue: bias + store. C/D: col=lane&15, row=(lane>>4)*4+reg
  float* Og = wn ? O1 : O0;
  const float* bg = wn ? bias1 : bias0;
#pragma unroll
  for (int nf = 0; nf < 4; ++nf) {
    const int ncol = head * HSn + nt * 64 + nf * 16 + l15;
    const float bv = bg[ncol];
#pragma unroll
    for (int mf = 0; mf < 4; ++mf) {
      const int rbase = mt * 256 + wm * 64 + mf * 16 + l4 * 4;
#pragma unroll
      for (int jx = 0; jx < 4; ++jx)
        Og[(size_t)(rbase + jx) * Hn + ncol] = acc[mf][nf][jx] + bv;
    }
  }
}

// ---------------------------------------------------------------- post ------
__global__ __launch_bounds__(256) void post_kernel(
    const float* __restrict__ x, const float* __restrict__ cell_state,
    const float* __restrict__ norm_state, const float* __restrict__ max_state,
    const float* __restrict__ gn_w, const float* __restrict__ gn_b,
    float* __restrict__ dout) {
  const size_t BH = (size_t)Bn * Hn;
  const int blk = blockIdx.x;
  const int b = blk >> 2;
  const int n = blk & 3;
  const int t = threadIdx.x;
  const int col = n * HSn + t * 4;
  const size_t off = (size_t)b * Hn + col;

  float iv[4], fv[4], zv[4], ov[4], csv[4], nsv[4], msv[4], xv[4];
  *(float4*)iv = *(const float4*)(dout + 4 * BH + off);
  *(float4*)fv = *(const float4*)(dout + 5 * BH + off);
  *(float4*)zv = *(const float4*)(dout + 6 * BH + off);
  *(float4*)ov = *(const float4*)(dout + 7 * BH + off);
  *(float4*)csv = *(const float4*)(cell_state + off);
  *(float4*)nsv = *(const float4*)(norm_state + off);
  *(float4*)msv = *(const float4*)(max_state + off);
  *(float4*)xv = *(const float4*)(x + off);

  float yv[4], cnv[4], nnv[4], mnv[4];
  float s = 0.f, s2 = 0.f;
#pragma unroll
  for (int j = 0; j < 4; ++j) {
    const float fj = fv[j];
    const float ls =
        (fj >= 0.f) ? -log1pf(expf(-fj)) : (fj - log1pf(expf(fj)));
    const float lfm = msv[j] + ls;
    const float mn = fmaxf(iv[j], lfm);
    const float ig = expf(iv[j] - mn);
    const float fg = expf(lfm - mn);
    const float cn = fg * csv[j] + ig * tanhf(zv[j]);
    const float nn = fg * nsv[j] + ig;
    const float so = 1.f / (1.f + expf(-ov[j]));
    const float y = so * cn / (nn + 1e-6f);
    yv[j] = y; cnv[j] = cn; nnv[j] = nn; mnv[j] = mn;
    s += y; s2 += y * y;
  }
  *(float4*)(dout + 4 * BH + off) = *(float4*)yv;
  *(float4*)(dout + 5 * BH + off) = *(float4*)cnv;
  *(float4*)(dout + 6 * BH + off) = *(float4*)nnv;
  *(float4*)(dout + 7 * BH + off) = *(float4*)mnv;

#pragma unroll
  for (int o2 = 32; o2 >= 1; o2 >>= 1) {
    s += __shfl_down(s, o2);
    s2 += __shfl_down(s2, o2);
  }
  __shared__ float red[10];
  const int lane = t & 63, wv = t >> 6;
  if (lane == 0) { red[wv] = s; red[4 + wv] = s2; }
  __syncthreads();
  if (t == 0) {
    float ts = red[0] + red[1] + red[2] + red[3];
    float ts2 = red[4] + red[5] + red[6] + red[7];
    float mean = ts * (1.f / HSn);
    float var = ts2 * (1.f / HSn) - mean * mean;
    red[8] = mean;
    red[9] = rsqrtf(var + 1e-5f);
  }
  __syncthreads();
  const float gm = red[8], grs = red[9];
  float gw[4], gb[4], outv[4];
  *(float4*)gw = *(const float4*)(gn_w + col);
  *(float4*)gb = *(const float4*)(gn_b + col);
#pragma unroll
  for (int j = 0; j < 4; ++j)
    outv[j] = (yv[j] - gm) * grs * gw[j] + gb[j] + xv[j];
  *(float4*)(dout + off) = *(float4*)outv;
}

// --------------------------------------------------------------- launch -----
extern "C" void kernel_launch(void* const* d_in, const int* in_sizes, int n_in,
                              void* d_out, int out_size, void* d_ws,
                              size_t ws_size, hipStream_t stream) {
  const float* x = (const float*)d_in[0];
  const float* cs = (const float*)d_in[1];
  const float* rst = (const float*)d_in[2];
  const float* cell = (const float*)d_in[3];
  const float* norm = (const float*)d_in[4];
  const float* maxs = (const float*)d_in[5];
  const float* ln_w = (const float*)d_in[6];
  const float* conv_w = (const float*)d_in[7];
  const float* conv_b = (const float*)d_in[8];
  const float* Wi_in = (const float*)d_in[9];
  const float* Wf_in = (const float*)d_in[10];
  const float* Wz_in = (const float*)d_in[11];
  const float* Wo_in = (const float*)d_in[12];
  const float* Wi_st = (const float*)d_in[13];
  const float* Wf_st = (const float*)d_in[14];
  const float* Wz_st = (const float*)d_in[15];
  const float* Wo_st = (const float*)d_in[16];
  const float* bi = (const float*)d_in[17];
  const float* bf_ = (const float*)d_in[18];
  const float* bz = (const float*)d_in[19];
  const float* bo = (const float*)d_in[20];
  const float* gn_w = (const float*)d_in[21];
  const float* gn_b = (const float*)d_in[22];

  float* out = (float*)d_out;
  const size_t BH = (size_t)Bn * Hn;
  float* slot0 = out;            // xact_split, later final out
  float* ncs = out + BH;         // slots 1-3: new_conv_state (B,3,H)
  const float* xn = ncs + 2 * (size_t)Hn;  // xn rows at stride 3H
  float* slot4 = out + 4 * BH;   // xn_split -> i -> y
  float* slot5 = out + 5 * BH;   // f -> cell
  float* slot6 = out + 6 * BH;   // z -> norm
  float* slot7 = out + 7 * BH;   // xact_fp32 -> o -> max
  char* wsR = (char*)d_ws;       // rst_split (32MB)

  hipLaunchKernelGGL(prep_kernel, dim3(Bn), dim3(256), 0, stream, x, cs, ln_w,
                     conv_w, conv_b, slot7, ncs);
  hipLaunchKernelGGL(tile_kernel, dim3(128, 3), dim3(256), 0, stream, slot7,
                     xn, rst, (char*)slot0, (char*)slot4, wsR);
  hipLaunchKernelGGL(gemm_pair_mfma, dim3(512), dim3(512), 0, stream,
                     (const char*)slot4, wsR, Wz_in, Wz_st, Wo_in, Wo_st, bz,
                     bo, slot6, slot7);
  hipLaunchKernelGGL(gemm_pair_mfma, dim3(512), dim3(512), 0, stream,
                     (const char*)slot0, wsR, Wi_in, Wi_st, Wf_in, Wf_st, bi,
                     bf_, slot4, slot5);
  hipLaunchKernelGGL(post_kernel, dim3(Bn * NHn), dim3(256), 0, stream, x, cell,
                     norm, maxs, gn_w, gn_b, out);
}